// Round 17
// baseline (4243.962 us; speedup 1.0000x reference)
//
#include <hip/hip_runtime.h>
#include <math.h>

#define HH 512
#define DD 512
#define BB 64
#define SS 256
#define KK 1024
#define CC 5

typedef __attribute__((ext_vector_type(8))) short short8;
typedef __attribute__((ext_vector_type(4))) float float4v;

// ---- workspace layout (bytes) ----  total used 100,926,464 (<= 101,188,608)
#define OFF_XEF     0u               // 256 s x 2 sp x 64 b x 512 k shorts = 33.5 MB
#define OFF_ROT     33554432u        // 257 slots x 256KB: [t][plane][dir][b][h] bf16
#define ROT_SLOT_B  262144u          // bytes per slot
#define OFF_FLG     100925440u       // 256 x 4B flags
#define OFF_POOLED  0u               // pooled overlays xef (dead after recurrence)

__device__ __forceinline__ unsigned f2bf_bits(float f) {
    unsigned u = __builtin_bit_cast(unsigned, f);
    return (u + 0x7fffu + ((u >> 16) & 1u)) >> 16;   // RNE
}
__device__ __forceinline__ float sigm_(float v) {
    return 1.f / (1.f + expf(-v));
}
__device__ __forceinline__ float tanh_(float v) {
    return tanhf(v);
}

// ---------------------------------------------------------------------------
// Gather embeddings + split hi/lo bf16 into xef[s][sp][b][k].
// ---------------------------------------------------------------------------
__global__ __launch_bounds__(256)
void gather_split_k(const int* __restrict__ x, const float* __restrict__ embed,
                    short* __restrict__ xef)
{
    const int s   = blockIdx.x;
    const int tid = threadIdx.x;
    const int b   = tid & 63;
    const int seg = tid >> 6;            // 4 segs x 128 k
    __shared__ int rows[BB];
    if (tid < BB) rows[tid] = x[tid * SS + s];   // x is [B][S]
    __syncthreads();
    const float* e = embed + (size_t)rows[b] * DD + seg * 128;
    short* oh = xef + ((size_t)(s * 2 + 0) * BB + b) * 512 + seg * 128;
    short* ol = xef + ((size_t)(s * 2 + 1) * BB + b) * 512 + seg * 128;
    for (int k0 = 0; k0 < 128; k0 += 8) {
        const float4 a = *(const float4*)(e + k0);
        const float4 c = *(const float4*)(e + k0 + 4);
        const float ev[8] = {a.x, a.y, a.z, a.w, c.x, c.y, c.z, c.w};
        short8 vh, vl;
        #pragma unroll
        for (int j = 0; j < 8; ++j) {
            const unsigned hib = f2bf_bits(ev[j]);
            const float hif = __builtin_bit_cast(float, hib << 16);
            const unsigned lob = f2bf_bits(ev[j] - hif);
            vh[j] = (short)hib;
            vl[j] = (short)lob;
        }
        *(short8*)(oh + k0) = vh;
        *(short8*)(ol + k0) = vl;
    }
}

// ---------------------------------------------------------------------------
__global__ __launch_bounds__(256)
void zero_k(unsigned* __restrict__ base, int ndw)
{
    int i = blockIdx.x * 256 + threadIdx.x;
    const int stride = gridDim.x * 256;
    for (; i < ndw; i += stride) base[i] = 0u;
}

// ---------------------------------------------------------------------------
// Cooperative recurrence: 256 WGs x 256 thr (1 WG/CU). R26 = R13-proven body
// (2034us) with ONE change: LOOP ROTATION to overlap the serially-exposed
// step tail (publish agent-ack ~600-1000cy + barrier) with the next step's
// x-phase. New order per iteration:
//   spin(t) -> h-phase(t) -> gates(t) -> publish-issue(t) ->
//   x-phase(t+1) [R13's exact block, fresh acc] -> vmcnt(0) [drains publish
//   stores AND x-loads, max not sum] -> barrier -> flag(t+1)
// All WGs shift identically so relative skew at the spin is unchanged.
// Per-step arithmetic is bit-identical to R13 — pure code motion. VGPR stays
// ~80-90: R16's failure (absmax identical to R1/R2) identified extreme
// register pressure (>~200 VGPR) as a miscompilation trigger; this kernel
// deliberately stays in the proven-safe pressure zone.
// ---------------------------------------------------------------------------
__global__ void __launch_bounds__(256, 1)
bilstm_recur_k(const short* __restrict__ xef,
               const float* __restrict__ fwd_W, const float* __restrict__ bwd_W,
               const float* __restrict__ fwd_b, const float* __restrict__ bwd_b,
               short* __restrict__ rot, unsigned* __restrict__ flg)
{
    extern __shared__ char smem[];
    short8* wlds = (short8*)smem;                           // 64 KB W fragments
    char*   hbuf = smem + 65536;                            // 64 KB staged h plane
    float*  ex   = (float*)(smem + 131072);                 // 4 KB exchange
    unsigned short* stg = (unsigned short*)(smem + 135168); // 1 KB publish stage

    const int w      = blockIdx.x;
    const int dir    = w >> 7;
    const int wlocal = w & 127;
    const int h0     = wlocal << 2;
    const int tid    = threadIdx.x;
    const int lane   = tid & 63;
    const int wv     = __builtin_amdgcn_readfirstlane(tid >> 6);
    const int n0     = wv << 4;
    const int nn     = lane & 15;
    const int quad   = lane >> 4;

    // ---- pack this WG's W fragments straight into LDS (bit-identical to
    //      wpack_k: f2bf_bits split of W[(g*H+h0+hh)][kt*32+quad*8+j]) ----
    {
        const float* W = dir ? bwd_W : fwd_W;
        const int m  = lane & 15;
        const int g  = m >> 2;
        const int hh = m & 3;
        const float* wrow = W + ((size_t)g * HH + h0 + hh) * KK + quad * 8;
        for (int kk = 0; kk < 8; ++kk) {
            const int kt = wv * 8 + kk;          // 4 waves x 8 = 32 kt
            const float4 a  = *(const float4*)(wrow + kt * 32);
            const float4 c4 = *(const float4*)(wrow + kt * 32 + 4);
            const float ev[8] = {a.x, a.y, a.z, a.w, c4.x, c4.y, c4.z, c4.w};
            short8 vh, vl;
            #pragma unroll
            for (int j = 0; j < 8; ++j) {
                const unsigned hib = f2bf_bits(ev[j]);
                const float hif = __builtin_bit_cast(float, hib << 16);
                const unsigned lob = f2bf_bits(ev[j] - hif);
                vh[j] = (short)hib;
                vl[j] = (short)lob;
            }
            wlds[(0 * 32 + kt) * 64 + lane] = vh;
            wlds[(1 * 32 + kt) * 64 + lane] = vl;
        }
    }
    __syncthreads();

    const float* bi = dir ? bwd_b : fwd_b;
    const float4 biasv = *(const float4*)(bi + quad * HH + h0);
    const float bias_arr[4] = {biasv.x, biasv.y, biasv.z, biasv.w};

    unsigned* myflg = flg + dir * 128;
    float* exw = ex + wv * 256;
    unsigned short* stgw = stg + wv * 128;   // per-wave publish stage
    const int b = n0 + nn;

    // ---- x-phase for step t (R13's exact block), as a macro so prologue
    //      and rotated loop share one definition ----
#define XPHASE(SIDX, ACC)                                                     \
    {                                                                         \
        const short8* xh8 = (const short8*)(xef +                             \
            ((size_t)((SIDX) * 2 + 0) * BB + b) * 512 + quad * 8);            \
        const short8* xl8 = (const short8*)(xef +                             \
            ((size_t)((SIDX) * 2 + 1) * BB + b) * 512 + quad * 8);            \
        _Pragma("unroll")                                                     \
        for (int kt = 0; kt < 16; ++kt) {                                     \
            const short8 xh  = xh8[kt * 4];                                   \
            const short8 xl  = xl8[kt * 4];                                   \
            const short8 whi = wlds[(0 * 32 + kt) * 64 + lane];               \
            const short8 wlo = wlds[(1 * 32 + kt) * 64 + lane];               \
            ACC = __builtin_amdgcn_mfma_f32_16x16x32_bf16(whi, xh, ACC, 0, 0, 0); \
            ACC = __builtin_amdgcn_mfma_f32_16x16x32_bf16(whi, xl, ACC, 0, 0, 0); \
            ACC = __builtin_amdgcn_mfma_f32_16x16x32_bf16(wlo, xh, ACC, 0, 0, 0); \
        }                                                                     \
    }

    // ---- prologue: x-phase for t=0 ----
    float4v acc = {0.f, 0.f, 0.f, 0.f};
    {
        const int s0 = dir ? (SS - 1) : 0;
        XPHASE(s0, acc)
    }

    for (int t = 0; t < SS; ++t) {
        const int s = dir ? (SS - 1 - t) : t;

        // ---------- wait: all WGs of this dir finished step t-1 ----------
        if (t > 0) {
            const unsigned tgt = (unsigned)t;
            unsigned va, vb;
            va = __hip_atomic_load(myflg + lane, __ATOMIC_RELAXED,
                                   __HIP_MEMORY_SCOPE_AGENT);
            vb = __hip_atomic_load(myflg + 64 + lane, __ATOMIC_RELAXED,
                                   __HIP_MEMORY_SCOPE_AGENT);
            while (__any(va < tgt || vb < tgt)) {
                __builtin_amdgcn_s_sleep(32);
                va = __hip_atomic_load(myflg + lane, __ATOMIC_RELAXED,
                                       __HIP_MEMORY_SCOPE_AGENT);
                vb = __hip_atomic_load(myflg + 64 + lane, __ATOMIC_RELAXED,
                                       __HIP_MEMORY_SCOPE_AGENT);
            }
            asm volatile("" ::: "memory");
        }

        // ---------- h-part: per-wave coalesced stage -> own LDS rows ------
        {
            const char* slot = (const char*)rot + (size_t)t * ROT_SLOT_B
                             + (size_t)dir * 65536;
            const short8* hq = (const short8*)(slot);            // hi plane
            const short8* lq = (const short8*)(slot + 131072);   // lo plane

            short8 sh[16], sl[16];
            #pragma unroll
            for (int it = 0; it < 16; ++it)
                sh[it] = hq[(n0 + it) * 64 + lane];
            #pragma unroll
            for (int it = 0; it < 16; ++it)
                sl[it] = lq[(n0 + it) * 64 + lane];

            // ---- hi plane into own swizzled rows (wave-synchronous) ----
            #pragma unroll
            for (int it = 0; it < 16; ++it) {
                const int r = n0 + it;
                *(short8*)(hbuf + ((r << 10) |
                    ((lane * 16) ^ ((r & 7) << 4)))) = sh[it];
            }
            #pragma unroll
            for (int kt = 0; kt < 16; ++kt) {
                const short8 uh = *(const short8*)(hbuf + ((b << 10) |
                    ((quad * 16 + kt * 64) ^ ((b & 7) << 4))));
                const short8 whi = wlds[(0 * 32 + 16 + kt) * 64 + lane];
                const short8 wlo = wlds[(1 * 32 + 16 + kt) * 64 + lane];
                acc = __builtin_amdgcn_mfma_f32_16x16x32_bf16(whi, uh, acc, 0, 0, 0);
                acc = __builtin_amdgcn_mfma_f32_16x16x32_bf16(wlo, uh, acc, 0, 0, 0);
            }

            // ---- lo plane reuses the same rows (within-wave WAR) ----
            #pragma unroll
            for (int it = 0; it < 16; ++it) {
                const int r = n0 + it;
                *(short8*)(hbuf + ((r << 10) |
                    ((lane * 16) ^ ((r & 7) << 4)))) = sl[it];
            }
            #pragma unroll
            for (int kt = 0; kt < 16; ++kt) {
                const short8 ul = *(const short8*)(hbuf + ((b << 10) |
                    ((quad * 16 + kt * 64) ^ ((b & 7) << 4))));
                const short8 whi = wlds[(0 * 32 + 16 + kt) * 64 + lane];
                acc = __builtin_amdgcn_mfma_f32_16x16x32_bf16(whi, ul, acc, 0, 0, 0);
            }
        }

        // ---------- bias + per-wave exchange ----------
        #pragma unroll
        for (int r2 = 0; r2 < 4; ++r2)
            exw[(quad * 4 + r2) * 16 + nn] = acc[r2] + bias_arr[r2];
        float pg[4];
        #pragma unroll
        for (int g_ = 0; g_ < 4; ++g_)
            pg[g_] = exw[(g_ * 4 + quad) * 16 + nn];

        const float f_  = sigm_(pg[0]);
        const float i_  = sigm_(pg[1]);
        const float ct  = tanh_(pg[2]);
        const float o_  = sigm_(pg[3]);
        const float c_  = (f_ + i_) * ct;      // faithful: prev cell unused
        const float hn  = o_ * tanh_(c_);

        const unsigned hib = f2bf_bits(hn);
        const float hif = __builtin_bit_cast(float, hib << 16);
        const unsigned lob = f2bf_bits(hn - hif);
        // per-wave stage: [plane][quad][nn]
        stgw[0 * 64 + quad * 16 + nn] = (unsigned short)hib;
        stgw[1 * 64 + quad * 16 + nn] = (unsigned short)lob;

        // ---------- publish into rot slot t+1 (per-wave, agent stores) ----
        {
            const int pl   = lane >> 5;          // 0 hi, 1 lo
            const int pair = (lane >> 4) & 1;
            const int n2   = lane & 15;
            const int pb   = n0 + n2;
            const unsigned v0 = stgw[pl * 64 + (pair * 2 + 0) * 16 + n2];
            const unsigned v1 = stgw[pl * 64 + (pair * 2 + 1) * 16 + n2];
            const unsigned val = v0 | (v1 << 16);
            const size_t so = (size_t)(t + 1) * 131072 + (size_t)pl * 65536
                            + (size_t)dir * 32768 + (size_t)pb * 512
                            + h0 + pair * 2;             // short index
            unsigned* dst = (unsigned*)(rot + so);
            __hip_atomic_store(dst, val, __ATOMIC_RELAXED,
                               __HIP_MEMORY_SCOPE_AGENT);
        }

        // ---------- x-phase for t+1 (overlaps the publish-ack drain) ------
        float4v accn = {0.f, 0.f, 0.f, 0.f};
        if (t + 1 < SS) {
            const int sn = dir ? (SS - 2 - t) : (t + 1);
            XPHASE(sn, accn)
        }

        asm volatile("s_waitcnt vmcnt(0)" ::: "memory");
        __syncthreads();        // sole barrier: all publishes acked
        if (tid == 0)
            __hip_atomic_store(myflg + wlocal, (unsigned)(t + 1),
                               __ATOMIC_RELAXED, __HIP_MEMORY_SCOPE_AGENT);

        acc = accn;
    }
#undef XPHASE
}

// ---------------------------------------------------------------------------
// Pool from the rotation buffer: reconstruct h = hi + lo (error ~1e-5, well
// under the 2.94e-4 threshold; recurrence numerics are unchanged since MFMA
// always consumed exactly these hi/lo splits).
// ---------------------------------------------------------------------------
__global__ __launch_bounds__(256)
void pool_k(const short* __restrict__ rot, float* __restrict__ pooled)
{
    const int tg = blockIdx.x * 256 + threadIdx.x;   // 32768 = 64 b x 512 h
    const int b  = tg >> 9;
    const int h  = tg & 511;
    const int off = b * 512 + h;
    float m = -2.0f;
    for (int s = 0; s < SS; ++s) {
        const short* fs = rot + (size_t)(s + 1) * 131072;
        const short* bs = rot + (size_t)(SS - s) * 131072;
        const unsigned hf = (unsigned short)fs[off];             // plane0 dir0
        const unsigned lf = (unsigned short)fs[65536 + off];     // plane1 dir0
        const unsigned hb = (unsigned short)bs[32768 + off];     // plane0 dir1
        const unsigned lb = (unsigned short)bs[65536 + 32768 + off];
        const float af = __builtin_bit_cast(float, hf << 16)
                       + __builtin_bit_cast(float, lf << 16);
        const float ab = __builtin_bit_cast(float, hb << 16)
                       + __builtin_bit_cast(float, lb << 16);
        m = fmaxf(m, tanhf(af * ab));
    }
    pooled[(size_t)h * BB + b] = m;
}

__global__ __launch_bounds__(256)
void outgemm_k(const float* __restrict__ pooled, const float* __restrict__ Wout,
               const float* __restrict__ bout, float* __restrict__ out)
{
    const int c   = blockIdx.x;
    const int tid = threadIdx.x;
    const int b   = tid & 63;
    const int q   = __builtin_amdgcn_readfirstlane(tid >> 6);
    float p = 0.0f;
    for (int j = 0; j < 128; ++j) {
        const int h = q * 128 + j;
        p = fmaf(pooled[(size_t)h * BB + b], Wout[c * HH + h], p);
    }
    __shared__ float red[4][BB];
    red[q][b] = p;
    __syncthreads();
    if (tid < BB)
        out[tid * CC + c] = red[0][tid] + red[1][tid] + red[2][tid] + red[3][tid] + bout[c];
}

// ---------------------------------------------------------------------------
extern "C" void kernel_launch(void* const* d_in, const int* in_sizes, int n_in,
                              void* d_out, int out_size, void* d_ws, size_t ws_size,
                              hipStream_t stream)
{
    const int*   x     = (const int*)d_in[0];
    const float* embed = (const float*)d_in[1];
    const float* fwd_W = (const float*)d_in[2];
    const float* fwd_b = (const float*)d_in[3];
    const float* bwd_W = (const float*)d_in[4];
    const float* bwd_b = (const float*)d_in[5];
    const float* Wout  = (const float*)d_in[6];
    const float* bout  = (const float*)d_in[7];
    float* out = (float*)d_out;

    char* wsb = (char*)d_ws;
    short*    xef    = (short*)(wsb + OFF_XEF);
    short*    rot    = (short*)(wsb + OFF_ROT);
    unsigned* flg    = (unsigned*)(wsb + OFF_FLG);
    float*    pooled = (float*)(wsb + OFF_POOLED);   // overlays xef (dead)

    gather_split_k<<<SS, 256, 0, stream>>>(x, embed, xef);
    zero_k<<<64, 256, 0, stream>>>((unsigned*)(wsb + OFF_ROT),
                                   (int)(ROT_SLOT_B / 4));   // slot 0
    zero_k<<<1, 256, 0, stream>>>(flg, 256);                 // flags

    hipFuncSetAttribute((const void*)bilstm_recur_k,
                        hipFuncAttributeMaxDynamicSharedMemorySize, 136192);
    void* args[] = {(void*)&xef, (void*)&fwd_W, (void*)&bwd_W,
                    (void*)&fwd_b, (void*)&bwd_b,
                    (void*)&rot, (void*)&flg};
    hipLaunchCooperativeKernel((void*)bilstm_recur_k, dim3(256), dim3(256),
                               args, 136192, stream);

    pool_k<<<128, 256, 0, stream>>>(rot, pooled);
    outgemm_k<<<CC, 256, 0, stream>>>(pooled, Wout, bout, out);
}

// Round 18
// 2105.016 us; speedup vs baseline: 2.0161x; 2.0161x over previous
//
#include <hip/hip_runtime.h>
#include <math.h>

#define HH 512
#define DD 512
#define BB 64
#define SS 256
#define KK 1024
#define CC 5

typedef __attribute__((ext_vector_type(8))) short short8;
typedef __attribute__((ext_vector_type(4))) float float4v;

// ---- workspace layout (bytes) ----  total used 100,926,464 (<= 101,188,608)
#define OFF_XEF     0u               // 256 s x 2 sp x 64 b x 512 k shorts = 33.5 MB
#define OFF_ROT     33554432u        // 257 slots x 256KB: [t][plane][dir][b][h] bf16
#define ROT_SLOT_B  262144u          // bytes per slot
#define OFF_FLG     100925440u       // 256 x 4B flags
#define OFF_POOLED  0u               // pooled overlays xef (dead after recurrence)

__device__ __forceinline__ unsigned f2bf_bits(float f) {
    unsigned u = __builtin_bit_cast(unsigned, f);
    return (u + 0x7fffu + ((u >> 16) & 1u)) >> 16;   // RNE
}
__device__ __forceinline__ float sigm_(float v) {
    return 1.f / (1.f + expf(-v));
}
__device__ __forceinline__ float tanh_(float v) {
    return tanhf(v);
}

// ---------------------------------------------------------------------------
// Gather embeddings + split hi/lo bf16 into xef[s][sp][b][k].
// ---------------------------------------------------------------------------
__global__ __launch_bounds__(256)
void gather_split_k(const int* __restrict__ x, const float* __restrict__ embed,
                    short* __restrict__ xef)
{
    const int s   = blockIdx.x;
    const int tid = threadIdx.x;
    const int b   = tid & 63;
    const int seg = tid >> 6;            // 4 segs x 128 k
    __shared__ int rows[BB];
    if (tid < BB) rows[tid] = x[tid * SS + s];   // x is [B][S]
    __syncthreads();
    const float* e = embed + (size_t)rows[b] * DD + seg * 128;
    short* oh = xef + ((size_t)(s * 2 + 0) * BB + b) * 512 + seg * 128;
    short* ol = xef + ((size_t)(s * 2 + 1) * BB + b) * 512 + seg * 128;
    for (int k0 = 0; k0 < 128; k0 += 8) {
        const float4 a = *(const float4*)(e + k0);
        const float4 c = *(const float4*)(e + k0 + 4);
        const float ev[8] = {a.x, a.y, a.z, a.w, c.x, c.y, c.z, c.w};
        short8 vh, vl;
        #pragma unroll
        for (int j = 0; j < 8; ++j) {
            const unsigned hib = f2bf_bits(ev[j]);
            const float hif = __builtin_bit_cast(float, hib << 16);
            const unsigned lob = f2bf_bits(ev[j] - hif);
            vh[j] = (short)hib;
            vl[j] = (short)lob;
        }
        *(short8*)(oh + k0) = vh;
        *(short8*)(ol + k0) = vl;
    }
}

// ---------------------------------------------------------------------------
__global__ __launch_bounds__(256)
void zero_k(unsigned* __restrict__ base, int ndw)
{
    int i = blockIdx.x * 256 + threadIdx.x;
    const int stride = gridDim.x * 256;
    for (; i < ndw; i += stride) base[i] = 0u;
}

// ---------------------------------------------------------------------------
// Cooperative recurrence: 256 WGs x 256 thr (1 WG/CU). R28 = R13-proven body
// (2034us) with ONE change: the spin's s_sleep(32) backoff is REMOVED (pure
// busy-poll). R17's 2x regression identified s_sleep quantization as a chain
// amplifier: a consumer that misses the flags by any margin pays a full
// 0.85us sleep quantum, stretching its own chain and cascading straggle to
// the next step. R13's 7.9us/step exceeds the serial-chain estimate (~5us)
// by ~2-3 quanta — consistent with 2-3 sleeps/step in steady state. Busy-
// poll contention was proven harmless in R0/R3 (identical timing with and
// without backoff at the old structure, same flag protocol).
// Everything else byte-identical to R13.
// ---------------------------------------------------------------------------
__global__ void __launch_bounds__(256, 1)
bilstm_recur_k(const short* __restrict__ xef,
               const float* __restrict__ fwd_W, const float* __restrict__ bwd_W,
               const float* __restrict__ fwd_b, const float* __restrict__ bwd_b,
               short* __restrict__ rot, unsigned* __restrict__ flg)
{
    extern __shared__ char smem[];
    short8* wlds = (short8*)smem;                           // 64 KB W fragments
    char*   hbuf = smem + 65536;                            // 64 KB staged h plane
    float*  ex   = (float*)(smem + 131072);                 // 4 KB exchange
    unsigned short* stg = (unsigned short*)(smem + 135168); // 1 KB publish stage

    const int w      = blockIdx.x;
    const int dir    = w >> 7;
    const int wlocal = w & 127;
    const int h0     = wlocal << 2;
    const int tid    = threadIdx.x;
    const int lane   = tid & 63;
    const int wv     = __builtin_amdgcn_readfirstlane(tid >> 6);
    const int n0     = wv << 4;
    const int nn     = lane & 15;
    const int quad   = lane >> 4;

    // ---- pack this WG's W fragments straight into LDS (bit-identical to
    //      wpack_k: f2bf_bits split of W[(g*H+h0+hh)][kt*32+quad*8+j]) ----
    {
        const float* W = dir ? bwd_W : fwd_W;
        const int m  = lane & 15;
        const int g  = m >> 2;
        const int hh = m & 3;
        const float* wrow = W + ((size_t)g * HH + h0 + hh) * KK + quad * 8;
        for (int kk = 0; kk < 8; ++kk) {
            const int kt = wv * 8 + kk;          // 4 waves x 8 = 32 kt
            const float4 a  = *(const float4*)(wrow + kt * 32);
            const float4 c4 = *(const float4*)(wrow + kt * 32 + 4);
            const float ev[8] = {a.x, a.y, a.z, a.w, c4.x, c4.y, c4.z, c4.w};
            short8 vh, vl;
            #pragma unroll
            for (int j = 0; j < 8; ++j) {
                const unsigned hib = f2bf_bits(ev[j]);
                const float hif = __builtin_bit_cast(float, hib << 16);
                const unsigned lob = f2bf_bits(ev[j] - hif);
                vh[j] = (short)hib;
                vl[j] = (short)lob;
            }
            wlds[(0 * 32 + kt) * 64 + lane] = vh;
            wlds[(1 * 32 + kt) * 64 + lane] = vl;
        }
    }
    __syncthreads();

    const float* bi = dir ? bwd_b : fwd_b;
    const float4 biasv = *(const float4*)(bi + quad * HH + h0);
    const float bias_arr[4] = {biasv.x, biasv.y, biasv.z, biasv.w};

    unsigned* myflg = flg + dir * 128;
    float* exw = ex + wv * 256;
    unsigned short* stgw = stg + wv * 128;   // per-wave publish stage
    const int b = n0 + nn;

    for (int t = 0; t < SS; ++t) {
        const int s = dir ? (SS - 1 - t) : t;

        float4v acc = {0.f, 0.f, 0.f, 0.f};

        // ---------- x-part: contiguous fragment loads from xef ----------
        {
            const short8* xh8 = (const short8*)(xef +
                ((size_t)(s * 2 + 0) * BB + b) * 512 + quad * 8);
            const short8* xl8 = (const short8*)(xef +
                ((size_t)(s * 2 + 1) * BB + b) * 512 + quad * 8);
            #pragma unroll
            for (int kt = 0; kt < 16; ++kt) {
                const short8 xh  = xh8[kt * 4];
                const short8 xl  = xl8[kt * 4];
                const short8 whi = wlds[(0 * 32 + kt) * 64 + lane];
                const short8 wlo = wlds[(1 * 32 + kt) * 64 + lane];
                acc = __builtin_amdgcn_mfma_f32_16x16x32_bf16(whi, xh, acc, 0, 0, 0);
                acc = __builtin_amdgcn_mfma_f32_16x16x32_bf16(whi, xl, acc, 0, 0, 0);
                acc = __builtin_amdgcn_mfma_f32_16x16x32_bf16(wlo, xh, acc, 0, 0, 0);
            }
        }

        // ---------- wait: busy-poll, no sleep (R17 lesson: sleep quantum
        //            amplifies straggle into a quantization cascade) ------
        if (t > 0) {
            const unsigned tgt = (unsigned)t;
            unsigned va, vb;
            do {
                va = __hip_atomic_load(myflg + lane, __ATOMIC_RELAXED,
                                       __HIP_MEMORY_SCOPE_AGENT);
                vb = __hip_atomic_load(myflg + 64 + lane, __ATOMIC_RELAXED,
                                       __HIP_MEMORY_SCOPE_AGENT);
            } while (__any(va < tgt || vb < tgt));
            asm volatile("" ::: "memory");
        }

        // ---------- h-part: per-wave coalesced stage -> own LDS rows ------
        {
            const char* slot = (const char*)rot + (size_t)t * ROT_SLOT_B
                             + (size_t)dir * 65536;
            const short8* hq = (const short8*)(slot);            // hi plane
            const short8* lq = (const short8*)(slot + 131072);   // lo plane

            short8 sh[16], sl[16];
            #pragma unroll
            for (int it = 0; it < 16; ++it)
                sh[it] = hq[(n0 + it) * 64 + lane];
            #pragma unroll
            for (int it = 0; it < 16; ++it)
                sl[it] = lq[(n0 + it) * 64 + lane];

            // ---- hi plane into own swizzled rows (wave-synchronous) ----
            #pragma unroll
            for (int it = 0; it < 16; ++it) {
                const int r = n0 + it;
                *(short8*)(hbuf + ((r << 10) |
                    ((lane * 16) ^ ((r & 7) << 4)))) = sh[it];
            }
            #pragma unroll
            for (int kt = 0; kt < 16; ++kt) {
                const short8 uh = *(const short8*)(hbuf + ((b << 10) |
                    ((quad * 16 + kt * 64) ^ ((b & 7) << 4))));
                const short8 whi = wlds[(0 * 32 + 16 + kt) * 64 + lane];
                const short8 wlo = wlds[(1 * 32 + 16 + kt) * 64 + lane];
                acc = __builtin_amdgcn_mfma_f32_16x16x32_bf16(whi, uh, acc, 0, 0, 0);
                acc = __builtin_amdgcn_mfma_f32_16x16x32_bf16(wlo, uh, acc, 0, 0, 0);
            }

            // ---- lo plane reuses the same rows (within-wave WAR) ----
            #pragma unroll
            for (int it = 0; it < 16; ++it) {
                const int r = n0 + it;
                *(short8*)(hbuf + ((r << 10) |
                    ((lane * 16) ^ ((r & 7) << 4)))) = sl[it];
            }
            #pragma unroll
            for (int kt = 0; kt < 16; ++kt) {
                const short8 ul = *(const short8*)(hbuf + ((b << 10) |
                    ((quad * 16 + kt * 64) ^ ((b & 7) << 4))));
                const short8 whi = wlds[(0 * 32 + 16 + kt) * 64 + lane];
                acc = __builtin_amdgcn_mfma_f32_16x16x32_bf16(whi, ul, acc, 0, 0, 0);
            }
        }

        // ---------- bias + per-wave exchange ----------
        #pragma unroll
        for (int r2 = 0; r2 < 4; ++r2)
            exw[(quad * 4 + r2) * 16 + nn] = acc[r2] + bias_arr[r2];
        float pg[4];
        #pragma unroll
        for (int g_ = 0; g_ < 4; ++g_)
            pg[g_] = exw[(g_ * 4 + quad) * 16 + nn];

        const float f_  = sigm_(pg[0]);
        const float i_  = sigm_(pg[1]);
        const float ct  = tanh_(pg[2]);
        const float o_  = sigm_(pg[3]);
        const float c_  = (f_ + i_) * ct;      // faithful: prev cell unused
        const float hn  = o_ * tanh_(c_);

        const unsigned hib = f2bf_bits(hn);
        const float hif = __builtin_bit_cast(float, hib << 16);
        const unsigned lob = f2bf_bits(hn - hif);
        // per-wave stage: [plane][quad][nn]
        stgw[0 * 64 + quad * 16 + nn] = (unsigned short)hib;
        stgw[1 * 64 + quad * 16 + nn] = (unsigned short)lob;

        // ---------- publish into rot slot t+1 (per-wave, agent stores) ----
        {
            const int pl   = lane >> 5;          // 0 hi, 1 lo
            const int pair = (lane >> 4) & 1;
            const int n2   = lane & 15;
            const int pb   = n0 + n2;
            const unsigned v0 = stgw[pl * 64 + (pair * 2 + 0) * 16 + n2];
            const unsigned v1 = stgw[pl * 64 + (pair * 2 + 1) * 16 + n2];
            const unsigned val = v0 | (v1 << 16);
            const size_t so = (size_t)(t + 1) * 131072 + (size_t)pl * 65536
                            + (size_t)dir * 32768 + (size_t)pb * 512
                            + h0 + pair * 2;             // short index
            unsigned* dst = (unsigned*)(rot + so);
            __hip_atomic_store(dst, val, __ATOMIC_RELAXED,
                               __HIP_MEMORY_SCOPE_AGENT);
        }
        asm volatile("s_waitcnt vmcnt(0)" ::: "memory");
        __syncthreads();        // sole barrier: all publishes acked
        if (tid == 0)
            __hip_atomic_store(myflg + wlocal, (unsigned)(t + 1),
                               __ATOMIC_RELAXED, __HIP_MEMORY_SCOPE_AGENT);
    }
}

// ---------------------------------------------------------------------------
// Pool from the rotation buffer: reconstruct h = hi + lo (error ~1e-5, well
// under the 2.94e-4 threshold; recurrence numerics are unchanged since MFMA
// always consumed exactly these hi/lo splits).
// ---------------------------------------------------------------------------
__global__ __launch_bounds__(256)
void pool_k(const short* __restrict__ rot, float* __restrict__ pooled)
{
    const int tg = blockIdx.x * 256 + threadIdx.x;   // 32768 = 64 b x 512 h
    const int b  = tg >> 9;
    const int h  = tg & 511;
    const int off = b * 512 + h;
    float m = -2.0f;
    for (int s = 0; s < SS; ++s) {
        const short* fs = rot + (size_t)(s + 1) * 131072;
        const short* bs = rot + (size_t)(SS - s) * 131072;
        const unsigned hf = (unsigned short)fs[off];             // plane0 dir0
        const unsigned lf = (unsigned short)fs[65536 + off];     // plane1 dir0
        const unsigned hb = (unsigned short)bs[32768 + off];     // plane0 dir1
        const unsigned lb = (unsigned short)bs[65536 + 32768 + off];
        const float af = __builtin_bit_cast(float, hf << 16)
                       + __builtin_bit_cast(float, lf << 16);
        const float ab = __builtin_bit_cast(float, hb << 16)
                       + __builtin_bit_cast(float, lb << 16);
        m = fmaxf(m, tanhf(af * ab));
    }
    pooled[(size_t)h * BB + b] = m;
}

__global__ __launch_bounds__(256)
void outgemm_k(const float* __restrict__ pooled, const float* __restrict__ Wout,
               const float* __restrict__ bout, float* __restrict__ out)
{
    const int c   = blockIdx.x;
    const int tid = threadIdx.x;
    const int b   = tid & 63;
    const int q   = __builtin_amdgcn_readfirstlane(tid >> 6);
    float p = 0.0f;
    for (int j = 0; j < 128; ++j) {
        const int h = q * 128 + j;
        p = fmaf(pooled[(size_t)h * BB + b], Wout[c * HH + h], p);
    }
    __shared__ float red[4][BB];
    red[q][b] = p;
    __syncthreads();
    if (tid < BB)
        out[tid * CC + c] = red[0][tid] + red[1][tid] + red[2][tid] + red[3][tid] + bout[c];
}

// ---------------------------------------------------------------------------
extern "C" void kernel_launch(void* const* d_in, const int* in_sizes, int n_in,
                              void* d_out, int out_size, void* d_ws, size_t ws_size,
                              hipStream_t stream)
{
    const int*   x     = (const int*)d_in[0];
    const float* embed = (const float*)d_in[1];
    const float* fwd_W = (const float*)d_in[2];
    const float* fwd_b = (const float*)d_in[3];
    const float* bwd_W = (const float*)d_in[4];
    const float* bwd_b = (const float*)d_in[5];
    const float* Wout  = (const float*)d_in[6];
    const float* bout  = (const float*)d_in[7];
    float* out = (float*)d_out;

    char* wsb = (char*)d_ws;
    short*    xef    = (short*)(wsb + OFF_XEF);
    short*    rot    = (short*)(wsb + OFF_ROT);
    unsigned* flg    = (unsigned*)(wsb + OFF_FLG);
    float*    pooled = (float*)(wsb + OFF_POOLED);   // overlays xef (dead)

    gather_split_k<<<SS, 256, 0, stream>>>(x, embed, xef);
    zero_k<<<64, 256, 0, stream>>>((unsigned*)(wsb + OFF_ROT),
                                   (int)(ROT_SLOT_B / 4));   // slot 0
    zero_k<<<1, 256, 0, stream>>>(flg, 256);                 // flags

    hipFuncSetAttribute((const void*)bilstm_recur_k,
                        hipFuncAttributeMaxDynamicSharedMemorySize, 136192);
    void* args[] = {(void*)&xef, (void*)&fwd_W, (void*)&bwd_W,
                    (void*)&fwd_b, (void*)&bwd_b,
                    (void*)&rot, (void*)&flg};
    hipLaunchCooperativeKernel((void*)bilstm_recur_k, dim3(256), dim3(256),
                               args, 136192, stream);

    pool_k<<<128, 256, 0, stream>>>(rot, pooled);
    outgemm_k<<<CC, 256, 0, stream>>>(pooled, Wout, bout, out);
}

// Round 19
// 2090.659 us; speedup vs baseline: 2.0300x; 1.0069x over previous
//
#include <hip/hip_runtime.h>
#include <math.h>

#define HH 512
#define DD 512
#define BB 64
#define SS 256
#define KK 1024
#define CC 5

typedef __attribute__((ext_vector_type(8))) short short8;
typedef __attribute__((ext_vector_type(4))) float float4v;

// ---- workspace layout (bytes) ----  total used 100,926,464 (<= 101,188,608)
#define OFF_XEF     0u               // 256 s x 2 sp x 64 b x 512 k shorts = 33.5 MB
#define OFF_ROT     33554432u        // 257 slots x 256KB: [t][plane][dir][b][h] bf16
#define ROT_SLOT_B  262144u          // bytes per slot
#define OFF_FLG     100925440u       // 256 x 4B flags
#define OFF_POOLED  0u               // pooled overlays xef (dead after recurrence)

__device__ __forceinline__ unsigned f2bf_bits(float f) {
    unsigned u = __builtin_bit_cast(unsigned, f);
    return (u + 0x7fffu + ((u >> 16) & 1u)) >> 16;   // RNE
}
__device__ __forceinline__ float sigm_(float v) {
    return 1.f / (1.f + expf(-v));
}
__device__ __forceinline__ float tanh_(float v) {
    return tanhf(v);
}

// ---------------------------------------------------------------------------
// Gather embeddings + split hi/lo bf16 into xef[s][sp][b][k].
// ---------------------------------------------------------------------------
__global__ __launch_bounds__(256)
void gather_split_k(const int* __restrict__ x, const float* __restrict__ embed,
                    short* __restrict__ xef)
{
    const int s   = blockIdx.x;
    const int tid = threadIdx.x;
    const int b   = tid & 63;
    const int seg = tid >> 6;            // 4 segs x 128 k
    __shared__ int rows[BB];
    if (tid < BB) rows[tid] = x[tid * SS + s];   // x is [B][S]
    __syncthreads();
    const float* e = embed + (size_t)rows[b] * DD + seg * 128;
    short* oh = xef + ((size_t)(s * 2 + 0) * BB + b) * 512 + seg * 128;
    short* ol = xef + ((size_t)(s * 2 + 1) * BB + b) * 512 + seg * 128;
    for (int k0 = 0; k0 < 128; k0 += 8) {
        const float4 a = *(const float4*)(e + k0);
        const float4 c = *(const float4*)(e + k0 + 4);
        const float ev[8] = {a.x, a.y, a.z, a.w, c.x, c.y, c.z, c.w};
        short8 vh, vl;
        #pragma unroll
        for (int j = 0; j < 8; ++j) {
            const unsigned hib = f2bf_bits(ev[j]);
            const float hif = __builtin_bit_cast(float, hib << 16);
            const unsigned lob = f2bf_bits(ev[j] - hif);
            vh[j] = (short)hib;
            vl[j] = (short)lob;
        }
        *(short8*)(oh + k0) = vh;
        *(short8*)(ol + k0) = vl;
    }
}

// ---------------------------------------------------------------------------
__global__ __launch_bounds__(256)
void zero_k(unsigned* __restrict__ base, int ndw)
{
    int i = blockIdx.x * 256 + threadIdx.x;
    const int stride = gridDim.x * 256;
    for (; i < ndw; i += stride) base[i] = 0u;
}

// ---------------------------------------------------------------------------
// Cooperative recurrence: 256 WGs x 256 thr (1 WG/CU). R30 = R13-proven body
// (2034us, sleep-32 spin) with ONE change: PARTIAL W HOIST. LDS-port
// arithmetic: ~144 x 1KB LDS ops/wave/step = ~2.4us/step of port time, the
// largest quantified component. The w0-plane h-part fragments (kt 16..31)
// are each read TWICE per step (h-hi + h-lo). Hoisting exactly those 16
// fragments into named registers (+64 VGPR -> ~136 total, inside the
// proven-safe band; R16's miscompile was at ~400) removes 32 reads/wave/step
// (~0.42us/step). Values and MFMA order bit-identical; h-loops become
// macros for compile-time register naming. Everything else byte-identical
// to R13.
// ---------------------------------------------------------------------------
__global__ void __launch_bounds__(256, 1)
bilstm_recur_k(const short* __restrict__ xef,
               const float* __restrict__ fwd_W, const float* __restrict__ bwd_W,
               const float* __restrict__ fwd_b, const float* __restrict__ bwd_b,
               short* __restrict__ rot, unsigned* __restrict__ flg)
{
    extern __shared__ char smem[];
    short8* wlds = (short8*)smem;                           // 64 KB W fragments
    char*   hbuf = smem + 65536;                            // 64 KB staged h plane
    float*  ex   = (float*)(smem + 131072);                 // 4 KB exchange
    unsigned short* stg = (unsigned short*)(smem + 135168); // 1 KB publish stage

    const int w      = blockIdx.x;
    const int dir    = w >> 7;
    const int wlocal = w & 127;
    const int h0     = wlocal << 2;
    const int tid    = threadIdx.x;
    const int lane   = tid & 63;
    const int wv     = __builtin_amdgcn_readfirstlane(tid >> 6);
    const int n0     = wv << 4;
    const int nn     = lane & 15;
    const int quad   = lane >> 4;

    // ---- pack this WG's W fragments straight into LDS (bit-identical to
    //      wpack_k: f2bf_bits split of W[(g*H+h0+hh)][kt*32+quad*8+j]) ----
    {
        const float* W = dir ? bwd_W : fwd_W;
        const int m  = lane & 15;
        const int g  = m >> 2;
        const int hh = m & 3;
        const float* wrow = W + ((size_t)g * HH + h0 + hh) * KK + quad * 8;
        for (int kk = 0; kk < 8; ++kk) {
            const int kt = wv * 8 + kk;          // 4 waves x 8 = 32 kt
            const float4 a  = *(const float4*)(wrow + kt * 32);
            const float4 c4 = *(const float4*)(wrow + kt * 32 + 4);
            const float ev[8] = {a.x, a.y, a.z, a.w, c4.x, c4.y, c4.z, c4.w};
            short8 vh, vl;
            #pragma unroll
            for (int j = 0; j < 8; ++j) {
                const unsigned hib = f2bf_bits(ev[j]);
                const float hif = __builtin_bit_cast(float, hib << 16);
                const unsigned lob = f2bf_bits(ev[j] - hif);
                vh[j] = (short)hib;
                vl[j] = (short)lob;
            }
            wlds[(0 * 32 + kt) * 64 + lane] = vh;
            wlds[(1 * 32 + kt) * 64 + lane] = vl;
        }
    }
    __syncthreads();

    // ---- hoist the 16 twice-read w0-plane h-part fragments (kt 16..31)
    //      into named registers (+64 VGPR; safe band) ----
#define WHOIST(i) const short8 wr_##i = wlds[(0 * 32 + (i)) * 64 + lane];
    WHOIST(16) WHOIST(17) WHOIST(18) WHOIST(19)
    WHOIST(20) WHOIST(21) WHOIST(22) WHOIST(23)
    WHOIST(24) WHOIST(25) WHOIST(26) WHOIST(27)
    WHOIST(28) WHOIST(29) WHOIST(30) WHOIST(31)
#undef WHOIST

    const float* bi = dir ? bwd_b : fwd_b;
    const float4 biasv = *(const float4*)(bi + quad * HH + h0);
    const float bias_arr[4] = {biasv.x, biasv.y, biasv.z, biasv.w};

    unsigned* myflg = flg + dir * 128;
    float* exw = ex + wv * 256;
    unsigned short* stgw = stg + wv * 128;   // per-wave publish stage
    const int b = n0 + nn;

    for (int t = 0; t < SS; ++t) {
        const int s = dir ? (SS - 1 - t) : t;

        float4v acc = {0.f, 0.f, 0.f, 0.f};

        // ---------- x-part: contiguous fragment loads from xef ----------
        {
            const short8* xh8 = (const short8*)(xef +
                ((size_t)(s * 2 + 0) * BB + b) * 512 + quad * 8);
            const short8* xl8 = (const short8*)(xef +
                ((size_t)(s * 2 + 1) * BB + b) * 512 + quad * 8);
            #pragma unroll
            for (int kt = 0; kt < 16; ++kt) {
                const short8 xh  = xh8[kt * 4];
                const short8 xl  = xl8[kt * 4];
                const short8 whi = wlds[(0 * 32 + kt) * 64 + lane];
                const short8 wlo = wlds[(1 * 32 + kt) * 64 + lane];
                acc = __builtin_amdgcn_mfma_f32_16x16x32_bf16(whi, xh, acc, 0, 0, 0);
                acc = __builtin_amdgcn_mfma_f32_16x16x32_bf16(whi, xl, acc, 0, 0, 0);
                acc = __builtin_amdgcn_mfma_f32_16x16x32_bf16(wlo, xh, acc, 0, 0, 0);
            }
        }

        // ---------- wait: all WGs of this dir finished step t-1 ----------
        if (t > 0) {
            const unsigned tgt = (unsigned)t;
            unsigned va, vb;
            va = __hip_atomic_load(myflg + lane, __ATOMIC_RELAXED,
                                   __HIP_MEMORY_SCOPE_AGENT);
            vb = __hip_atomic_load(myflg + 64 + lane, __ATOMIC_RELAXED,
                                   __HIP_MEMORY_SCOPE_AGENT);
            while (__any(va < tgt || vb < tgt)) {
                __builtin_amdgcn_s_sleep(32);
                va = __hip_atomic_load(myflg + lane, __ATOMIC_RELAXED,
                                       __HIP_MEMORY_SCOPE_AGENT);
                vb = __hip_atomic_load(myflg + 64 + lane, __ATOMIC_RELAXED,
                                       __HIP_MEMORY_SCOPE_AGENT);
            }
            asm volatile("" ::: "memory");
        }

        // ---------- h-part: per-wave coalesced stage -> own LDS rows ------
        {
            const char* slot = (const char*)rot + (size_t)t * ROT_SLOT_B
                             + (size_t)dir * 65536;
            const short8* hq = (const short8*)(slot);            // hi plane
            const short8* lq = (const short8*)(slot + 131072);   // lo plane

            short8 sh[16], sl[16];
            #pragma unroll
            for (int it = 0; it < 16; ++it)
                sh[it] = hq[(n0 + it) * 64 + lane];
            #pragma unroll
            for (int it = 0; it < 16; ++it)
                sl[it] = lq[(n0 + it) * 64 + lane];

            // ---- hi plane into own swizzled rows (wave-synchronous) ----
            #pragma unroll
            for (int it = 0; it < 16; ++it) {
                const int r = n0 + it;
                *(short8*)(hbuf + ((r << 10) |
                    ((lane * 16) ^ ((r & 7) << 4)))) = sh[it];
            }
#define HHI(i, iw)                                                            \
            {                                                                 \
                const short8 uh = *(const short8*)(hbuf + ((b << 10) |        \
                    ((quad * 16 + (i) * 64) ^ ((b & 7) << 4))));              \
                const short8 wlo = wlds[(1 * 32 + (iw)) * 64 + lane];         \
                acc = __builtin_amdgcn_mfma_f32_16x16x32_bf16(wr_##iw, uh, acc, 0, 0, 0); \
                acc = __builtin_amdgcn_mfma_f32_16x16x32_bf16(wlo, uh, acc, 0, 0, 0); \
            }
            HHI(0, 16)  HHI(1, 17)  HHI(2, 18)  HHI(3, 19)
            HHI(4, 20)  HHI(5, 21)  HHI(6, 22)  HHI(7, 23)
            HHI(8, 24)  HHI(9, 25)  HHI(10, 26) HHI(11, 27)
            HHI(12, 28) HHI(13, 29) HHI(14, 30) HHI(15, 31)
#undef HHI

            // ---- lo plane reuses the same rows (within-wave WAR) ----
            #pragma unroll
            for (int it = 0; it < 16; ++it) {
                const int r = n0 + it;
                *(short8*)(hbuf + ((r << 10) |
                    ((lane * 16) ^ ((r & 7) << 4)))) = sl[it];
            }
#define HLO(i, iw)                                                            \
            {                                                                 \
                const short8 ul = *(const short8*)(hbuf + ((b << 10) |        \
                    ((quad * 16 + (i) * 64) ^ ((b & 7) << 4))));              \
                acc = __builtin_amdgcn_mfma_f32_16x16x32_bf16(wr_##iw, ul, acc, 0, 0, 0); \
            }
            HLO(0, 16)  HLO(1, 17)  HLO(2, 18)  HLO(3, 19)
            HLO(4, 20)  HLO(5, 21)  HLO(6, 22)  HLO(7, 23)
            HLO(8, 24)  HLO(9, 25)  HLO(10, 26) HLO(11, 27)
            HLO(12, 28) HLO(13, 29) HLO(14, 30) HLO(15, 31)
#undef HLO
        }

        // ---------- bias + per-wave exchange ----------
        #pragma unroll
        for (int r2 = 0; r2 < 4; ++r2)
            exw[(quad * 4 + r2) * 16 + nn] = acc[r2] + bias_arr[r2];
        float pg[4];
        #pragma unroll
        for (int g_ = 0; g_ < 4; ++g_)
            pg[g_] = exw[(g_ * 4 + quad) * 16 + nn];

        const float f_  = sigm_(pg[0]);
        const float i_  = sigm_(pg[1]);
        const float ct  = tanh_(pg[2]);
        const float o_  = sigm_(pg[3]);
        const float c_  = (f_ + i_) * ct;      // faithful: prev cell unused
        const float hn  = o_ * tanh_(c_);

        const unsigned hib = f2bf_bits(hn);
        const float hif = __builtin_bit_cast(float, hib << 16);
        const unsigned lob = f2bf_bits(hn - hif);
        // per-wave stage: [plane][quad][nn]
        stgw[0 * 64 + quad * 16 + nn] = (unsigned short)hib;
        stgw[1 * 64 + quad * 16 + nn] = (unsigned short)lob;

        // ---------- publish into rot slot t+1 (per-wave, agent stores) ----
        {
            const int pl   = lane >> 5;          // 0 hi, 1 lo
            const int pair = (lane >> 4) & 1;
            const int n2   = lane & 15;
            const int pb   = n0 + n2;
            const unsigned v0 = stgw[pl * 64 + (pair * 2 + 0) * 16 + n2];
            const unsigned v1 = stgw[pl * 64 + (pair * 2 + 1) * 16 + n2];
            const unsigned val = v0 | (v1 << 16);
            const size_t so = (size_t)(t + 1) * 131072 + (size_t)pl * 65536
                            + (size_t)dir * 32768 + (size_t)pb * 512
                            + h0 + pair * 2;             // short index
            unsigned* dst = (unsigned*)(rot + so);
            __hip_atomic_store(dst, val, __ATOMIC_RELAXED,
                               __HIP_MEMORY_SCOPE_AGENT);
        }
        asm volatile("s_waitcnt vmcnt(0)" ::: "memory");
        __syncthreads();        // sole barrier: all publishes acked
        if (tid == 0)
            __hip_atomic_store(myflg + wlocal, (unsigned)(t + 1),
                               __ATOMIC_RELAXED, __HIP_MEMORY_SCOPE_AGENT);
    }
}

// ---------------------------------------------------------------------------
// Pool from the rotation buffer: reconstruct h = hi + lo (error ~1e-5, well
// under the 2.94e-4 threshold; recurrence numerics are unchanged since MFMA
// always consumed exactly these hi/lo splits).
// ---------------------------------------------------------------------------
__global__ __launch_bounds__(256)
void pool_k(const short* __restrict__ rot, float* __restrict__ pooled)
{
    const int tg = blockIdx.x * 256 + threadIdx.x;   // 32768 = 64 b x 512 h
    const int b  = tg >> 9;
    const int h  = tg & 511;
    const int off = b * 512 + h;
    float m = -2.0f;
    for (int s = 0; s < SS; ++s) {
        const short* fs = rot + (size_t)(s + 1) * 131072;
        const short* bs = rot + (size_t)(SS - s) * 131072;
        const unsigned hf = (unsigned short)fs[off];             // plane0 dir0
        const unsigned lf = (unsigned short)fs[65536 + off];     // plane1 dir0
        const unsigned hb = (unsigned short)bs[32768 + off];     // plane0 dir1
        const unsigned lb = (unsigned short)bs[65536 + 32768 + off];
        const float af = __builtin_bit_cast(float, hf << 16)
                       + __builtin_bit_cast(float, lf << 16);
        const float ab = __builtin_bit_cast(float, hb << 16)
                       + __builtin_bit_cast(float, lb << 16);
        m = fmaxf(m, tanhf(af * ab));
    }
    pooled[(size_t)h * BB + b] = m;
}

__global__ __launch_bounds__(256)
void outgemm_k(const float* __restrict__ pooled, const float* __restrict__ Wout,
               const float* __restrict__ bout, float* __restrict__ out)
{
    const int c   = blockIdx.x;
    const int tid = threadIdx.x;
    const int b   = tid & 63;
    const int q   = __builtin_amdgcn_readfirstlane(tid >> 6);
    float p = 0.0f;
    for (int j = 0; j < 128; ++j) {
        const int h = q * 128 + j;
        p = fmaf(pooled[(size_t)h * BB + b], Wout[c * HH + h], p);
    }
    __shared__ float red[4][BB];
    red[q][b] = p;
    __syncthreads();
    if (tid < BB)
        out[tid * CC + c] = red[0][tid] + red[1][tid] + red[2][tid] + red[3][tid] + bout[c];
}

// ---------------------------------------------------------------------------
extern "C" void kernel_launch(void* const* d_in, const int* in_sizes, int n_in,
                              void* d_out, int out_size, void* d_ws, size_t ws_size,
                              hipStream_t stream)
{
    const int*   x     = (const int*)d_in[0];
    const float* embed = (const float*)d_in[1];
    const float* fwd_W = (const float*)d_in[2];
    const float* fwd_b = (const float*)d_in[3];
    const float* bwd_W = (const float*)d_in[4];
    const float* bwd_b = (const float*)d_in[5];
    const float* Wout  = (const float*)d_in[6];
    const float* bout  = (const float*)d_in[7];
    float* out = (float*)d_out;

    char* wsb = (char*)d_ws;
    short*    xef    = (short*)(wsb + OFF_XEF);
    short*    rot    = (short*)(wsb + OFF_ROT);
    unsigned* flg    = (unsigned*)(wsb + OFF_FLG);
    float*    pooled = (float*)(wsb + OFF_POOLED);   // overlays xef (dead)

    gather_split_k<<<SS, 256, 0, stream>>>(x, embed, xef);
    zero_k<<<64, 256, 0, stream>>>((unsigned*)(wsb + OFF_ROT),
                                   (int)(ROT_SLOT_B / 4));   // slot 0
    zero_k<<<1, 256, 0, stream>>>(flg, 256);                 // flags

    hipFuncSetAttribute((const void*)bilstm_recur_k,
                        hipFuncAttributeMaxDynamicSharedMemorySize, 136192);
    void* args[] = {(void*)&xef, (void*)&fwd_W, (void*)&bwd_W,
                    (void*)&fwd_b, (void*)&bwd_b,
                    (void*)&rot, (void*)&flg};
    hipLaunchCooperativeKernel((void*)bilstm_recur_k, dim3(256), dim3(256),
                               args, 136192, stream);

    pool_k<<<128, 256, 0, stream>>>(rot, pooled);
    outgemm_k<<<CC, 256, 0, stream>>>(pooled, Wout, bout, out);
}

// Round 20
// 2089.904 us; speedup vs baseline: 2.0307x; 1.0004x over previous
//
#include <hip/hip_runtime.h>
#include <math.h>

#define HH 512
#define DD 512
#define BB 64
#define SS 256
#define KK 1024
#define CC 5

typedef __attribute__((ext_vector_type(8))) short short8;
typedef __attribute__((ext_vector_type(4))) float float4v;

// ---- workspace layout (bytes) ----  total used 100,929,536 (<= 101,188,608)
#define OFF_XEF     0u               // 256 s x 2 sp x 64 b x 512 k shorts = 33.5 MB
#define OFF_ROT     33554432u        // 257 slots x 256KB: [t][plane][dir][b][h] bf16
#define ROT_SLOT_B  262144u          // bytes per slot
#define OFF_FLG     100925440u       // 2 dir x 4 wv x 128 wg x 4B = 4 KB flags
#define OFF_POOLED  0u               // pooled overlays xef (dead after recurrence)

__device__ __forceinline__ unsigned f2bf_bits(float f) {
    unsigned u = __builtin_bit_cast(unsigned, f);
    return (u + 0x7fffu + ((u >> 16) & 1u)) >> 16;   // RNE
}
__device__ __forceinline__ float sigm_(float v) {
    return 1.f / (1.f + expf(-v));
}
__device__ __forceinline__ float tanh_(float v) {
    return tanhf(v);
}

// ---------------------------------------------------------------------------
// Gather embeddings + split hi/lo bf16 into xef[s][sp][b][k].
// ---------------------------------------------------------------------------
__global__ __launch_bounds__(256)
void gather_split_k(const int* __restrict__ x, const float* __restrict__ embed,
                    short* __restrict__ xef)
{
    const int s   = blockIdx.x;
    const int tid = threadIdx.x;
    const int b   = tid & 63;
    const int seg = tid >> 6;            // 4 segs x 128 k
    __shared__ int rows[BB];
    if (tid < BB) rows[tid] = x[tid * SS + s];   // x is [B][S]
    __syncthreads();
    const float* e = embed + (size_t)rows[b] * DD + seg * 128;
    short* oh = xef + ((size_t)(s * 2 + 0) * BB + b) * 512 + seg * 128;
    short* ol = xef + ((size_t)(s * 2 + 1) * BB + b) * 512 + seg * 128;
    for (int k0 = 0; k0 < 128; k0 += 8) {
        const float4 a = *(const float4*)(e + k0);
        const float4 c = *(const float4*)(e + k0 + 4);
        const float ev[8] = {a.x, a.y, a.z, a.w, c.x, c.y, c.z, c.w};
        short8 vh, vl;
        #pragma unroll
        for (int j = 0; j < 8; ++j) {
            const unsigned hib = f2bf_bits(ev[j]);
            const float hif = __builtin_bit_cast(float, hib << 16);
            const unsigned lob = f2bf_bits(ev[j] - hif);
            vh[j] = (short)hib;
            vl[j] = (short)lob;
        }
        *(short8*)(oh + k0) = vh;
        *(short8*)(ol + k0) = vl;
    }
}

// ---------------------------------------------------------------------------
__global__ __launch_bounds__(256)
void zero_k(unsigned* __restrict__ base, int ndw)
{
    int i = blockIdx.x * 256 + threadIdx.x;
    const int stride = gridDim.x * 256;
    for (; i < ndw; i += stride) base[i] = 0u;
}

// ---------------------------------------------------------------------------
// Cooperative recurrence: 256 WGs x 256 thr (1 WG/CU). R32 = R13-proven body
// (2034us) with ONE change: PER-WAVE FLAGS, NO IN-LOOP BARRIER. Audit of the
// R13 body shows the loop is fully per-wave independent (W-LDS read-only
// after prologue; hbuf rows, exw, stgw per-wave exclusive), and consumer
// wave wv reads exactly the b-block (n0..n0+15) published by wave wv of
// every WG. So flags become flg[dir][wv][wg]: wave wv publishes its b-block,
// drains with its own vmcnt(0), stores its own flag (lane 0) — no
// __syncthreads — and polls only the 128 wave-wv flags (same 2 loads/lane).
// Removes the last barrier + the per-step wait-for-slowest-wave-in-WG.
// Observer==loader holds per-wave; the rotation buffer already removed all
// WAR hazards. Arithmetic byte-identical to R13.
// ---------------------------------------------------------------------------
__global__ void __launch_bounds__(256, 1)
bilstm_recur_k(const short* __restrict__ xef,
               const float* __restrict__ fwd_W, const float* __restrict__ bwd_W,
               const float* __restrict__ fwd_b, const float* __restrict__ bwd_b,
               short* __restrict__ rot, unsigned* __restrict__ flg)
{
    extern __shared__ char smem[];
    short8* wlds = (short8*)smem;                           // 64 KB W fragments
    char*   hbuf = smem + 65536;                            // 64 KB staged h plane
    float*  ex   = (float*)(smem + 131072);                 // 4 KB exchange
    unsigned short* stg = (unsigned short*)(smem + 135168); // 1 KB publish stage

    const int w      = blockIdx.x;
    const int dir    = w >> 7;
    const int wlocal = w & 127;
    const int h0     = wlocal << 2;
    const int tid    = threadIdx.x;
    const int lane   = tid & 63;
    const int wv     = __builtin_amdgcn_readfirstlane(tid >> 6);
    const int n0     = wv << 4;
    const int nn     = lane & 15;
    const int quad   = lane >> 4;

    // ---- pack this WG's W fragments straight into LDS (bit-identical to
    //      wpack_k: f2bf_bits split of W[(g*H+h0+hh)][kt*32+quad*8+j]) ----
    {
        const float* W = dir ? bwd_W : fwd_W;
        const int m  = lane & 15;
        const int g  = m >> 2;
        const int hh = m & 3;
        const float* wrow = W + ((size_t)g * HH + h0 + hh) * KK + quad * 8;
        for (int kk = 0; kk < 8; ++kk) {
            const int kt = wv * 8 + kk;          // 4 waves x 8 = 32 kt
            const float4 a  = *(const float4*)(wrow + kt * 32);
            const float4 c4 = *(const float4*)(wrow + kt * 32 + 4);
            const float ev[8] = {a.x, a.y, a.z, a.w, c4.x, c4.y, c4.z, c4.w};
            short8 vh, vl;
            #pragma unroll
            for (int j = 0; j < 8; ++j) {
                const unsigned hib = f2bf_bits(ev[j]);
                const float hif = __builtin_bit_cast(float, hib << 16);
                const unsigned lob = f2bf_bits(ev[j] - hif);
                vh[j] = (short)hib;
                vl[j] = (short)lob;
            }
            wlds[(0 * 32 + kt) * 64 + lane] = vh;
            wlds[(1 * 32 + kt) * 64 + lane] = vl;
        }
    }
    __syncthreads();    // prologue barrier: wlds written by all waves

    const float* bi = dir ? bwd_b : fwd_b;
    const float4 biasv = *(const float4*)(bi + quad * HH + h0);
    const float bias_arr[4] = {biasv.x, biasv.y, biasv.z, biasv.w};

    // per-(dir, wv) flag group: 128 entries
    unsigned* myflg = flg + (size_t)(dir * 4 + wv) * 128;
    float* exw = ex + wv * 256;
    unsigned short* stgw = stg + wv * 128;   // per-wave publish stage
    const int b = n0 + nn;

    for (int t = 0; t < SS; ++t) {
        const int s = dir ? (SS - 1 - t) : t;

        float4v acc = {0.f, 0.f, 0.f, 0.f};

        // ---------- x-part: contiguous fragment loads from xef ----------
        {
            const short8* xh8 = (const short8*)(xef +
                ((size_t)(s * 2 + 0) * BB + b) * 512 + quad * 8);
            const short8* xl8 = (const short8*)(xef +
                ((size_t)(s * 2 + 1) * BB + b) * 512 + quad * 8);
            #pragma unroll
            for (int kt = 0; kt < 16; ++kt) {
                const short8 xh  = xh8[kt * 4];
                const short8 xl  = xl8[kt * 4];
                const short8 whi = wlds[(0 * 32 + kt) * 64 + lane];
                const short8 wlo = wlds[(1 * 32 + kt) * 64 + lane];
                acc = __builtin_amdgcn_mfma_f32_16x16x32_bf16(whi, xh, acc, 0, 0, 0);
                acc = __builtin_amdgcn_mfma_f32_16x16x32_bf16(whi, xl, acc, 0, 0, 0);
                acc = __builtin_amdgcn_mfma_f32_16x16x32_bf16(wlo, xh, acc, 0, 0, 0);
            }
        }

        // ---------- wait: the 128 wave-wv flags of this dir >= t ----------
        if (t > 0) {
            const unsigned tgt = (unsigned)t;
            unsigned va, vb;
            va = __hip_atomic_load(myflg + lane, __ATOMIC_RELAXED,
                                   __HIP_MEMORY_SCOPE_AGENT);
            vb = __hip_atomic_load(myflg + 64 + lane, __ATOMIC_RELAXED,
                                   __HIP_MEMORY_SCOPE_AGENT);
            while (__any(va < tgt || vb < tgt)) {
                __builtin_amdgcn_s_sleep(32);
                va = __hip_atomic_load(myflg + lane, __ATOMIC_RELAXED,
                                       __HIP_MEMORY_SCOPE_AGENT);
                vb = __hip_atomic_load(myflg + 64 + lane, __ATOMIC_RELAXED,
                                       __HIP_MEMORY_SCOPE_AGENT);
            }
            asm volatile("" ::: "memory");
        }

        // ---------- h-part: per-wave coalesced stage -> own LDS rows ------
        {
            const char* slot = (const char*)rot + (size_t)t * ROT_SLOT_B
                             + (size_t)dir * 65536;
            const short8* hq = (const short8*)(slot);            // hi plane
            const short8* lq = (const short8*)(slot + 131072);   // lo plane

            short8 sh[16], sl[16];
            #pragma unroll
            for (int it = 0; it < 16; ++it)
                sh[it] = hq[(n0 + it) * 64 + lane];
            #pragma unroll
            for (int it = 0; it < 16; ++it)
                sl[it] = lq[(n0 + it) * 64 + lane];

            // ---- hi plane into own swizzled rows (wave-synchronous) ----
            #pragma unroll
            for (int it = 0; it < 16; ++it) {
                const int r = n0 + it;
                *(short8*)(hbuf + ((r << 10) |
                    ((lane * 16) ^ ((r & 7) << 4)))) = sh[it];
            }
            #pragma unroll
            for (int kt = 0; kt < 16; ++kt) {
                const short8 uh = *(const short8*)(hbuf + ((b << 10) |
                    ((quad * 16 + kt * 64) ^ ((b & 7) << 4))));
                const short8 whi = wlds[(0 * 32 + 16 + kt) * 64 + lane];
                const short8 wlo = wlds[(1 * 32 + 16 + kt) * 64 + lane];
                acc = __builtin_amdgcn_mfma_f32_16x16x32_bf16(whi, uh, acc, 0, 0, 0);
                acc = __builtin_amdgcn_mfma_f32_16x16x32_bf16(wlo, uh, acc, 0, 0, 0);
            }

            // ---- lo plane reuses the same rows (within-wave WAR) ----
            #pragma unroll
            for (int it = 0; it < 16; ++it) {
                const int r = n0 + it;
                *(short8*)(hbuf + ((r << 10) |
                    ((lane * 16) ^ ((r & 7) << 4)))) = sl[it];
            }
            #pragma unroll
            for (int kt = 0; kt < 16; ++kt) {
                const short8 ul = *(const short8*)(hbuf + ((b << 10) |
                    ((quad * 16 + kt * 64) ^ ((b & 7) << 4))));
                const short8 whi = wlds[(0 * 32 + 16 + kt) * 64 + lane];
                acc = __builtin_amdgcn_mfma_f32_16x16x32_bf16(whi, ul, acc, 0, 0, 0);
            }
        }

        // ---------- bias + per-wave exchange ----------
        #pragma unroll
        for (int r2 = 0; r2 < 4; ++r2)
            exw[(quad * 4 + r2) * 16 + nn] = acc[r2] + bias_arr[r2];
        float pg[4];
        #pragma unroll
        for (int g_ = 0; g_ < 4; ++g_)
            pg[g_] = exw[(g_ * 4 + quad) * 16 + nn];

        const float f_  = sigm_(pg[0]);
        const float i_  = sigm_(pg[1]);
        const float ct  = tanh_(pg[2]);
        const float o_  = sigm_(pg[3]);
        const float c_  = (f_ + i_) * ct;      // faithful: prev cell unused
        const float hn  = o_ * tanh_(c_);

        const unsigned hib = f2bf_bits(hn);
        const float hif = __builtin_bit_cast(float, hib << 16);
        const unsigned lob = f2bf_bits(hn - hif);
        // per-wave stage: [plane][quad][nn]
        stgw[0 * 64 + quad * 16 + nn] = (unsigned short)hib;
        stgw[1 * 64 + quad * 16 + nn] = (unsigned short)lob;

        // ---------- publish into rot slot t+1 (per-wave, agent stores) ----
        {
            const int pl   = lane >> 5;          // 0 hi, 1 lo
            const int pair = (lane >> 4) & 1;
            const int n2   = lane & 15;
            const int pb   = n0 + n2;
            const unsigned v0 = stgw[pl * 64 + (pair * 2 + 0) * 16 + n2];
            const unsigned v1 = stgw[pl * 64 + (pair * 2 + 1) * 16 + n2];
            const unsigned val = v0 | (v1 << 16);
            const size_t so = (size_t)(t + 1) * 131072 + (size_t)pl * 65536
                            + (size_t)dir * 32768 + (size_t)pb * 512
                            + h0 + pair * 2;             // short index
            unsigned* dst = (unsigned*)(rot + so);
            __hip_atomic_store(dst, val, __ATOMIC_RELAXED,
                               __HIP_MEMORY_SCOPE_AGENT);
        }
        // per-wave drain + per-wave flag (no barrier: loop body is fully
        // per-wave independent; consumer wave wv reads only wave-wv data)
        asm volatile("s_waitcnt vmcnt(0)" ::: "memory");
        if (lane == 0)
            __hip_atomic_store(myflg + wlocal, (unsigned)(t + 1),
                               __ATOMIC_RELAXED, __HIP_MEMORY_SCOPE_AGENT);
    }
}

// ---------------------------------------------------------------------------
// Pool from the rotation buffer: reconstruct h = hi + lo (error ~1e-5, well
// under the 2.94e-4 threshold; recurrence numerics are unchanged since MFMA
// always consumed exactly these hi/lo splits).
// ---------------------------------------------------------------------------
__global__ __launch_bounds__(256)
void pool_k(const short* __restrict__ rot, float* __restrict__ pooled)
{
    const int tg = blockIdx.x * 256 + threadIdx.x;   // 32768 = 64 b x 512 h
    const int b  = tg >> 9;
    const int h  = tg & 511;
    const int off = b * 512 + h;
    float m = -2.0f;
    for (int s = 0; s < SS; ++s) {
        const short* fs = rot + (size_t)(s + 1) * 131072;
        const short* bs = rot + (size_t)(SS - s) * 131072;
        const unsigned hf = (unsigned short)fs[off];             // plane0 dir0
        const unsigned lf = (unsigned short)fs[65536 + off];     // plane1 dir0
        const unsigned hb = (unsigned short)bs[32768 + off];     // plane0 dir1
        const unsigned lb = (unsigned short)bs[65536 + 32768 + off];
        const float af = __builtin_bit_cast(float, hf << 16)
                       + __builtin_bit_cast(float, lf << 16);
        const float ab = __builtin_bit_cast(float, hb << 16)
                       + __builtin_bit_cast(float, lb << 16);
        m = fmaxf(m, tanhf(af * ab));
    }
    pooled[(size_t)h * BB + b] = m;
}

__global__ __launch_bounds__(256)
void outgemm_k(const float* __restrict__ pooled, const float* __restrict__ Wout,
               const float* __restrict__ bout, float* __restrict__ out)
{
    const int c   = blockIdx.x;
    const int tid = threadIdx.x;
    const int b   = tid & 63;
    const int q   = __builtin_amdgcn_readfirstlane(tid >> 6);
    float p = 0.0f;
    for (int j = 0; j < 128; ++j) {
        const int h = q * 128 + j;
        p = fmaf(pooled[(size_t)h * BB + b], Wout[c * HH + h], p);
    }
    __shared__ float red[4][BB];
    red[q][b] = p;
    __syncthreads();
    if (tid < BB)
        out[tid * CC + c] = red[0][tid] + red[1][tid] + red[2][tid] + red[3][tid] + bout[c];
}

// ---------------------------------------------------------------------------
extern "C" void kernel_launch(void* const* d_in, const int* in_sizes, int n_in,
                              void* d_out, int out_size, void* d_ws, size_t ws_size,
                              hipStream_t stream)
{
    const int*   x     = (const int*)d_in[0];
    const float* embed = (const float*)d_in[1];
    const float* fwd_W = (const float*)d_in[2];
    const float* fwd_b = (const float*)d_in[3];
    const float* bwd_W = (const float*)d_in[4];
    const float* bwd_b = (const float*)d_in[5];
    const float* Wout  = (const float*)d_in[6];
    const float* bout  = (const float*)d_in[7];
    float* out = (float*)d_out;

    char* wsb = (char*)d_ws;
    short*    xef    = (short*)(wsb + OFF_XEF);
    short*    rot    = (short*)(wsb + OFF_ROT);
    unsigned* flg    = (unsigned*)(wsb + OFF_FLG);
    float*    pooled = (float*)(wsb + OFF_POOLED);   // overlays xef (dead)

    gather_split_k<<<SS, 256, 0, stream>>>(x, embed, xef);
    zero_k<<<64, 256, 0, stream>>>((unsigned*)(wsb + OFF_ROT),
                                   (int)(ROT_SLOT_B / 4));   // slot 0
    zero_k<<<1, 256, 0, stream>>>(flg, 1024);                // per-wave flags

    hipFuncSetAttribute((const void*)bilstm_recur_k,
                        hipFuncAttributeMaxDynamicSharedMemorySize, 136192);
    void* args[] = {(void*)&xef, (void*)&fwd_W, (void*)&bwd_W,
                    (void*)&fwd_b, (void*)&bwd_b,
                    (void*)&rot, (void*)&flg};
    hipLaunchCooperativeKernel((void*)bilstm_recur_k, dim3(256), dim3(256),
                               args, 136192, stream);

    pool_k<<<128, 256, 0, stream>>>(rot, pooled);
    outgemm_k<<<CC, 256, 0, stream>>>(pooled, Wout, bout, out);
}